// Round 8
// baseline (190.853 us; speedup 1.0000x reference)
//
#include <hip/hip_runtime.h>
#include <math.h>

typedef _Float16 half8_t __attribute__((ext_vector_type(8)));
typedef _Float16 half4_t __attribute__((ext_vector_type(4)));
typedef _Float16 half2_t __attribute__((ext_vector_type(2)));
typedef float f32x4 __attribute__((ext_vector_type(4)));
typedef float f32x16 __attribute__((ext_vector_type(16)));
typedef unsigned int uint32x4 __attribute__((ext_vector_type(4)));

#define MFMA16(a, b, c) __builtin_amdgcn_mfma_f32_16x16x32_f16((a), (b), (c), 0, 0, 0)
#define MFMA32(a, b, c) __builtin_amdgcn_mfma_f32_32x32x16_f16((a), (b), (c), 0, 0, 0)

// log2(e) / sqrt(128): fold softmax scale AND exp->exp2 conversion into q.
#define SCALE_Q (0.08838834764831845f * 1.44269504088896340736f)

static __device__ inline unsigned int pkh(float a, float b) {
    half2_t h;
    h[0] = (_Float16)a;
    h[1] = (_Float16)b;
    return __builtin_bit_cast(unsigned int, h);
}

// ---------------------------------------------------------------------------
// Kernel 0: W [512][128] fp32  ->  Wt [128][512] fp16   (x3 for q,k,v)
// ---------------------------------------------------------------------------
__global__ __launch_bounds__(256) void wt_kernel(const float* __restrict__ Wq,
                                                 const float* __restrict__ Wk,
                                                 const float* __restrict__ Wv,
                                                 _Float16* __restrict__ WtAll) {
    int y = blockIdx.y;
    const float* W = (y == 0) ? Wq : (y == 1) ? Wk : Wv;
    int idx = blockIdx.x * 256 + threadIdx.x;
    int kk = idx >> 7;
    int d  = idx & 127;
    WtAll[y * 65536 + d * 512 + kk] = (_Float16)W[idx];
}

// ---------------------------------------------------------------------------
// Kernel 1: projection GEMM v5 — NO K-loop.  C[16384][128] = X @ W + b.
// Per block (32 s-rows): the ENTIRE W^T slice (128 KB) + X tile (16 KB,
// two 256-K halves through one buffer) live in LDS at once -> 144 KiB,
// 1 block/CU, grid (512,3) = 6 generations. 5 barriers per block total
// (was 17): the per-32K-step barrier+drain serializer (pinned ~41 us across
// 5 variants) is structurally gone. K-major LDS reads XOR-granule-swizzled
// (G4) on BOTH write and read (involution proven correct in R5's X stage).
// X half-1 loads issued before compute half-0 (T14).
// ---------------------------------------------------------------------------
__global__ __launch_bounds__(256) void proj_kernel(
    const float* __restrict__ q_in, const float* __restrict__ k_in,
    const float* __restrict__ v_in, const _Float16* __restrict__ WtAll,
    const float* __restrict__ biasq, const float* __restrict__ biask,
    const float* __restrict__ biasv,
    _Float16* __restrict__ qbuf, _Float16* __restrict__ kbuf,
    _Float16* __restrict__ vtbuf) {
    int y = blockIdx.y;
    const float* x = (y == 0) ? q_in : (y == 1) ? k_in : v_in;
    const _Float16* Wt = WtAll + y * 65536;
    const float* bias = (y == 0) ? biasq : (y == 1) ? biask : biasv;
    int row0 = blockIdx.x * 32;

    __shared__ _Float16 smem[73728];     // 147,456 B
    _Float16* Xlds = smem;               // [32][256]  (one K-half, swizzled)
    _Float16* Wlds = smem + 8192;        // [128][512] (full W^T, swizzled)

    int tid = threadIdx.x;
    int wave = tid >> 6, lane = tid & 63;
    int l32 = lane & 31, hi = lane >> 5, hi8 = hi * 8;
    int wn = wave * 32;                  // wave's 32 d-columns

    // X per-thread staging coords: row xr, 32 k starting at xk
    int xr = tid >> 3, xk = (tid & 7) * 32;
    const float* xrow = x + (size_t)(row0 + xr) * 512 + xk;

    // ---- issue X half-0 loads (8 x float4) ----
    float4 xa[8];
#pragma unroll
    for (int j = 0; j < 8; j++) xa[j] = ((const float4*)xrow)[j];

    // ---- stage W: 32 chunks x 2048 halfs, coalesced load, swizzled write --
    // chunk ch: thread t covers half-index ch*2048 + t*8
    //   -> d = ch*4 + wave, k-granule g = lane; write at g ^ (d&7).
    for (int cb = 0; cb < 32; cb += 8) {
        half8_t wv[8];
#pragma unroll
        for (int j = 0; j < 8; j++)
            wv[j] = *(const half8_t*)(Wt + (cb + j) * 2048 + tid * 8);
#pragma unroll
        for (int j = 0; j < 8; j++) {
            int d = (cb + j) * 4 + wave;
            int g = lane ^ (d & 7);
            *(half8_t*)&Wlds[d * 512 + g * 8] = wv[j];
        }
    }

    // ---- write X half-0 (fp32->fp16, swizzled) ----
#pragma unroll
    for (int m = 0; m < 4; m++) {
        float4 a0 = xa[2 * m], a1 = xa[2 * m + 1];
        half8_t h;
        h[0] = (_Float16)a0.x; h[1] = (_Float16)a0.y;
        h[2] = (_Float16)a0.z; h[3] = (_Float16)a0.w;
        h[4] = (_Float16)a1.x; h[5] = (_Float16)a1.y;
        h[6] = (_Float16)a1.z; h[7] = (_Float16)a1.w;
        int g = ((tid & 7) * 4 + m) ^ (xr & 7);
        *(half8_t*)&Xlds[xr * 256 + g * 8] = h;
    }

    // ---- issue X half-1 loads now; they land during compute half-0 (T14) --
    float4 xb[8];
#pragma unroll
    for (int j = 0; j < 8; j++) xb[j] = ((const float4*)(xrow + 256))[j];

    __syncthreads();

    int dd = wn + l32;                   // this lane's d column
    int dx = dd & 7;                     // = l32 & 7 (wn multiple of 32)
    f32x16 acc = {};

    // ---- compute half-0: k = 0..255 (16 MFMA32 steps) ----
    __builtin_amdgcn_s_setprio(1);
#pragma unroll
    for (int ks = 0; ks < 16; ks++) {
        half8_t af =
            *(const half8_t*)&Xlds[l32 * 256 + (((ks * 2 + hi) ^ dx) * 8)];
        half8_t bf =
            *(const half8_t*)&Wlds[dd * 512 + (((ks * 2 + hi) ^ dx) * 8)];
        acc = MFMA32(af, bf, acc);
    }
    __builtin_amdgcn_s_setprio(0);

    __syncthreads();   // all waves done reading X half-0

    // ---- write X half-1 into the same buffer ----
#pragma unroll
    for (int m = 0; m < 4; m++) {
        float4 a0 = xb[2 * m], a1 = xb[2 * m + 1];
        half8_t h;
        h[0] = (_Float16)a0.x; h[1] = (_Float16)a0.y;
        h[2] = (_Float16)a0.z; h[3] = (_Float16)a0.w;
        h[4] = (_Float16)a1.x; h[5] = (_Float16)a1.y;
        h[6] = (_Float16)a1.z; h[7] = (_Float16)a1.w;
        int g = ((tid & 7) * 4 + m) ^ (xr & 7);
        *(half8_t*)&Xlds[xr * 256 + g * 8] = h;
    }
    __syncthreads();

    // ---- compute half-1: k = 256..511 ----
    __builtin_amdgcn_s_setprio(1);
#pragma unroll
    for (int ks = 0; ks < 16; ks++) {
        half8_t af =
            *(const half8_t*)&Xlds[l32 * 256 + (((ks * 2 + hi) ^ dx) * 8)];
        int gks = ks + 16;
        half8_t bf =
            *(const half8_t*)&Wlds[dd * 512 + (((gks * 2 + hi) ^ dx) * 8)];
        acc = MFMA32(af, bf, acc);
    }
    __builtin_amdgcn_s_setprio(0);

    __syncthreads();   // X/W dead; overlay epilogue tile at smem[0]

    // ---- epilogue: bias (+scale), LDS transpose, coalesced stores --------
    float scale = (y == 0) ? SCALE_Q : 1.0f;
    float bc = bias[dd];
    if (y < 2) {
        // row-major [32][136] tile
#pragma unroll
        for (int r = 0; r < 16; r++) {
            int crow = (r & 3) + 8 * (r >> 2) + 4 * hi;
            smem[crow * 136 + dd] = (_Float16)((acc[r] + bc) * scale);
        }
        __syncthreads();
        int srow = tid >> 3, sc = (tid & 7) * 16;
        _Float16* outp =
            ((y == 0) ? qbuf : kbuf) + (size_t)(row0 + srow) * 128 + sc;
        *(half8_t*)(outp)     = *(const half8_t*)&smem[srow * 136 + sc];
        *(half8_t*)(outp + 8) = *(const half8_t*)&smem[srow * 136 + sc + 8];
    } else {
        // transposed [128][40] tile (20.5 KB, overlays dead X + head of W)
#pragma unroll
        for (int rq = 0; rq < 4; rq++) {
            half4_t pk;
#pragma unroll
            for (int rr = 0; rr < 4; rr++)
                pk[rr] = (_Float16)(acc[rq * 4 + rr] + bc);
            *(half4_t*)&smem[dd * 40 + rq * 8 + 4 * hi] = pk;
        }
        __syncthreads();
        int d = tid >> 1, off = (tid & 1) * 16;
        int bbn = row0 >> 11, s0 = row0 & 2047;
        _Float16* outp = vtbuf + ((size_t)bbn * 128 + d) * 2048 + s0 + off;
        *(half8_t*)(outp)     = *(const half8_t*)&smem[d * 40 + off];
        *(half8_t*)(outp + 8) = *(const half8_t*)&smem[d * 40 + off + 8];
    }
}

// ---------------------------------------------------------------------------
// Kernel 2: flash attention, 32x32 MFMA, in-register P (no Pt LDS).
// XCD-aware mapping (T1): bb = blockIdx.x & 7. 1 block = 64 q rows, 8 waves:
// {g = kv-half} x {qsub} x {kt}. Swapped QK^T (S^T = K Q^T) puts q = lane&31;
// softmax folds with ONE shfl_xor(32); P -> PV B-operand via cross-hi
// exchange (T12). O^T in regs; 4 partial (O,m,l) chains merged in LDS at end.
// ---------------------------------------------------------------------------
__global__ __launch_bounds__(512, 2) void attn_kernel(
    const _Float16* __restrict__ qbuf, const _Float16* __restrict__ kbuf,
    const _Float16* __restrict__ vtbuf, float* __restrict__ out) {
    int bb = blockIdx.x & 7;            // XCD-aligned batch mapping (T1)
    int q0 = (blockIdx.x >> 3) * 64;
    int tid = threadIdx.x, wave = tid >> 6, lane = tid & 63;
    int g = wave >> 2, qsub = (wave >> 1) & 1, kt = wave & 1;
    int l32 = lane & 31, hi = lane >> 5, hi8 = hi * 8;

    __shared__ _Float16 smem[71680];   // 143,360 B
    _Float16* KsA = smem + g * 35840;            // [64][136]
    _Float16* KsB = KsA + 8704;
    _Float16* VsA = smem + g * 35840 + 17408;    // [128][72]  (V^T: [d][key])
    _Float16* VsB = VsA + 9216;

    // Q fragments: B-frag for 32x32x16: B[k=hi*8+j][q=l32]
    half8_t qf[8];
    {
        const _Float16* qrow =
            qbuf + ((size_t)bb * 2048 + q0 + qsub * 32 + l32) * 128 + hi8;
#pragma unroll
        for (int kc = 0; kc < 8; kc++)
            qf[kc] = *(const half8_t*)(qrow + kc * 16);
    }

    const _Float16* kbase = kbuf + ((size_t)bb * 2048 + g * 1024) * 128;
    const _Float16* vbase = vtbuf + (size_t)bb * 128 * 2048 + g * 1024;

    int tg = tid & 255;                           // thread within kv-group
    int krow = tg >> 2, kcol = (tg & 3) * 32;     // K stage: 64 x 128
    int vrow = tg >> 1, vcol = (tg & 1) * 32;     // V stage: 128 x 64

    // prologue: stage tile 0 into buffer A
    {
        const half8_t* ks = (const half8_t*)(kbase + (size_t)krow * 128 + kcol);
        half8_t k0 = ks[0], k1 = ks[1], k2 = ks[2], k3 = ks[3];
        const half8_t* vs = (const half8_t*)(vbase + (size_t)vrow * 2048 + vcol);
        half8_t v0 = vs[0], v1 = vs[1], v2 = vs[2], v3 = vs[3];
        *(half8_t*)&KsA[krow * 136 + kcol]      = k0;
        *(half8_t*)&KsA[krow * 136 + kcol + 8]  = k1;
        *(half8_t*)&KsA[krow * 136 + kcol + 16] = k2;
        *(half8_t*)&KsA[krow * 136 + kcol + 24] = k3;
        *(half8_t*)&VsA[vrow * 72 + vcol]       = v0;
        *(half8_t*)&VsA[vrow * 72 + vcol + 8]   = v1;
        *(half8_t*)&VsA[vrow * 72 + vcol + 16]  = v2;
        *(half8_t*)&VsA[vrow * 72 + vcol + 24]  = v3;
    }
    __syncthreads();

    f32x16 acc0 = {}, acc1 = {}, acc2 = {}, acc3 = {};
    float m = -INFINITY, l = 0.0f;

    for (int it = 0; it < 16; ++it) {
        bool more = it < 15;
        half8_t nk0, nk1, nk2, nk3, nv0, nv1, nv2, nv3;
        if (more) {   // T14: issue next-tile loads before compute
            const half8_t* ks =
                (const half8_t*)(kbase + (size_t)((it + 1) * 64 + krow) * 128 + kcol);
            nk0 = ks[0]; nk1 = ks[1]; nk2 = ks[2]; nk3 = ks[3];
            const half8_t* vs =
                (const half8_t*)(vbase + (size_t)vrow * 2048 + (it + 1) * 64 + vcol);
            nv0 = vs[0]; nv1 = vs[1]; nv2 = vs[2]; nv3 = vs[3];
        }

        // S^T[key][q] = K Q^T for this wave's 32 keys (kt subtile)
        f32x16 sf = {};
        __builtin_amdgcn_s_setprio(1);
#pragma unroll
        for (int kc = 0; kc < 8; kc++) {
            half8_t kf =
                *(const half8_t*)&KsA[(kt * 32 + l32) * 136 + kc * 16 + hi8];
            sf = MFMA32(kf, qf[kc], sf);
        }
        __builtin_amdgcn_s_setprio(0);

        // online softmax; q = l32 per lane; keys split across hi halves
        float mx = sf[0];
#pragma unroll
        for (int i = 1; i < 16; i++) mx = fmaxf(mx, sf[i]);
        mx = fmaxf(mx, __shfl_xor(mx, 32, 64));
        if (!__all(mx <= m + 8.0f)) {   // T13 defer-max (THR=8)
            float mn = fmaxf(m, mx);
            float al = exp2f(m - mn);
            l *= al;
            acc0 *= al; acc1 *= al; acc2 *= al; acc3 *= al;
            m = mn;
        }
        float p[16];
        float rs = 0.0f;
#pragma unroll
        for (int i = 0; i < 16; i++) {
            p[i] = exp2f(sf[i] - m);
            rs += p[i];
        }
        rs += __shfl_xor(rs, 32, 64);
        l += rs;

        // pack P (key = (r&3)+8*(r>>2)+4*hi), cross-hi exchange -> B-frags
        unsigned int u0 = pkh(p[0], p[1]),   u1 = pkh(p[2], p[3]);
        unsigned int u2 = pkh(p[4], p[5]),   u3 = pkh(p[6], p[7]);
        unsigned int u4 = pkh(p[8], p[9]),   u5 = pkh(p[10], p[11]);
        unsigned int u6 = pkh(p[12], p[13]), u7 = pkh(p[14], p[15]);
        unsigned int x00 = hi ? u0 : u2, x01 = hi ? u1 : u3;
        unsigned int x10 = hi ? u4 : u6, x11 = hi ? u5 : u7;
        unsigned int r00 = __shfl_xor(x00, 32, 64), r01 = __shfl_xor(x01, 32, 64);
        unsigned int r10 = __shfl_xor(x10, 32, 64), r11 = __shfl_xor(x11, 32, 64);
        uint32x4 b0u, b1u;
        b0u[0] = hi ? r00 : u0; b0u[1] = hi ? r01 : u1;
        b0u[2] = hi ? u2 : r00; b0u[3] = hi ? u3 : r01;
        b1u[0] = hi ? r10 : u4; b1u[1] = hi ? r11 : u5;
        b1u[2] = hi ? u6 : r10; b1u[3] = hi ? u7 : r11;
        half8_t pb0 = __builtin_bit_cast(half8_t, b0u);
        half8_t pb1 = __builtin_bit_cast(half8_t, b1u);

        // O^T[d][q] += V^T P^T  (A = V^T rows d, B = P^T cols q)
        __builtin_amdgcn_s_setprio(1);
        {
            half8_t v0 = *(const half8_t*)&VsA[(0 * 32 + l32) * 72 + kt * 32 + hi8];
            acc0 = MFMA32(v0, pb0, acc0);
            half8_t v1 = *(const half8_t*)&VsA[(0 * 32 + l32) * 72 + kt * 32 + 16 + hi8];
            acc0 = MFMA32(v1, pb1, acc0);
            half8_t v2 = *(const half8_t*)&VsA[(1 * 32 + l32) * 72 + kt * 32 + hi8];
            acc1 = MFMA32(v2, pb0, acc1);
            half8_t v3 = *(const half8_t*)&VsA[(1 * 32 + l32) * 72 + kt * 32 + 16 + hi8];
            acc1 = MFMA32(v3, pb1, acc1);
            half8_t v4 = *(const half8_t*)&VsA[(2 * 32 + l32) * 72 + kt * 32 + hi8];
            acc2 = MFMA32(v4, pb0, acc2);
            half8_t v5 = *(const half8_t*)&VsA[(2 * 32 + l32) * 72 + kt * 32 + 16 + hi8];
            acc2 = MFMA32(v5, pb1, acc2);
            half8_t v6 = *(const half8_t*)&VsA[(3 * 32 + l32) * 72 + kt * 32 + hi8];
            acc3 = MFMA32(v6, pb0, acc3);
            half8_t v7 = *(const half8_t*)&VsA[(3 * 32 + l32) * 72 + kt * 32 + 16 + hi8];
            acc3 = MFMA32(v7, pb1, acc3);
        }
        __builtin_amdgcn_s_setprio(0);

        if (more) {
            *(half8_t*)&KsB[krow * 136 + kcol]      = nk0;
            *(half8_t*)&KsB[krow * 136 + kcol + 8]  = nk1;
            *(half8_t*)&KsB[krow * 136 + kcol + 16] = nk2;
            *(half8_t*)&KsB[krow * 136 + kcol + 24] = nk3;
            *(half8_t*)&VsB[vrow * 72 + vcol]       = nv0;
            *(half8_t*)&VsB[vrow * 72 + vcol + 8]   = nv1;
            *(half8_t*)&VsB[vrow * 72 + vcol + 16]  = nv2;
            *(half8_t*)&VsB[vrow * 72 + vcol + 24]  = nv3;
        }
        __syncthreads();
        _Float16* tmp;
        tmp = KsA; KsA = KsB; KsB = tmp;
        tmp = VsA; VsA = VsB; VsB = tmp;
    }

    // -----------------------------------------------------------------------
    // Merge the 4 partial chains (g,kt) per qsub. Tree: kt-pairs, then g-pairs.
    // Scratch overlays dead K/V LDS: R1[4 regions][128][33] f32 + ml[4][64].
    // -----------------------------------------------------------------------
    float* R1 = (float*)smem;
    const int RS = 33;
    int wid2 = g * 2 + qsub;
    float* Om = R1 + wid2 * (128 * RS);
    float* Ml = R1 + 4 * 128 * RS + wid2 * 64;

#define STORE_ACC(DST, A, DT)                                             \
    {                                                                     \
        _Pragma("unroll") for (int r = 0; r < 16; r++) {                  \
            int d = (r & 3) + 8 * (r >> 2) + 4 * hi + 32 * (DT);          \
            (DST)[d * RS + l32] = (A)[r];                                 \
        }                                                                 \
    }
#define MERGE_ACC(SRC, A, DT)                                             \
    {                                                                     \
        _Pragma("unroll") for (int r = 0; r < 16; r++) {                  \
            int d = (r & 3) + 8 * (r >> 2) + 4 * hi + 32 * (DT);          \
            (A)[r] = (A)[r] * sa + (SRC)[d * RS + l32] * sb;              \
        }                                                                 \
    }

    if (kt == 1) {
        STORE_ACC(Om, acc0, 0); STORE_ACC(Om, acc1, 1);
        STORE_ACC(Om, acc2, 2); STORE_ACC(Om, acc3, 3);
        if (hi == 0) { Ml[l32] = m; Ml[32 + l32] = l; }
    }
    __syncthreads();
    if (kt == 0) {
        float m1 = Ml[l32], l1 = Ml[32 + l32];
        float mf = fmaxf(m, m1);
        float sa = exp2f(m - mf), sb = exp2f(m1 - mf);
        l = l * sa + l1 * sb;
        m = mf;
        MERGE_ACC(Om, acc0, 0); MERGE_ACC(Om, acc1, 1);
        MERGE_ACC(Om, acc2, 2); MERGE_ACC(Om, acc3, 3);
    }
    __syncthreads();
    if (kt == 0 && g == 1) {
        float* Om2 = R1 + qsub * (128 * RS);
        float* Ml2 = R1 + 4 * 128 * RS + qsub * 64;
        STORE_ACC(Om2, acc0, 0); STORE_ACC(Om2, acc1, 1);
        STORE_ACC(Om2, acc2, 2); STORE_ACC(Om2, acc3, 3);
        if (hi == 0) { Ml2[l32] = m; Ml2[32 + l32] = l; }
    }
    __syncthreads();
    if (kt == 0 && g == 0) {
        float* Om2 = R1 + qsub * (128 * RS);
        float* Ml2 = R1 + 4 * 128 * RS + qsub * 64;
        float m1 = Ml2[l32], l1 = Ml2[32 + l32];
        float mf = fmaxf(m, m1);
        float sa = exp2f(m - mf), sb = exp2f(m1 - mf);
        float lf = l * sa + l1 * sb;
        float inv = 1.0f / lf;
        float* op = out + ((size_t)bb * 2048 + q0 + qsub * 32 + l32) * 128;
#define FINAL_ACC(A, DT)                                                  \
        {                                                                 \
            _Pragma("unroll") for (int r = 0; r < 16; r++) {              \
                int d = (r & 3) + 8 * (r >> 2) + 4 * hi + 32 * (DT);      \
                op[d] = ((A)[r] * sa + Om2[d * RS + l32] * sb) * inv;     \
            }                                                             \
        }
        FINAL_ACC(acc0, 0); FINAL_ACC(acc1, 1);
        FINAL_ACC(acc2, 2); FINAL_ACC(acc3, 3);
#undef FINAL_ACC
    }
#undef STORE_ACC
#undef MERGE_ACC
}

// ---------------------------------------------------------------------------
extern "C" void kernel_launch(void* const* d_in, const int* in_sizes, int n_in,
                              void* d_out, int out_size, void* d_ws,
                              size_t ws_size, hipStream_t stream) {
    const float* q_in = (const float*)d_in[0];
    const float* k_in = (const float*)d_in[1];
    const float* v_in = (const float*)d_in[2];
    const float* Wq = (const float*)d_in[3];
    const float* Wk = (const float*)d_in[4];
    const float* Wv = (const float*)d_in[5];
    const float* bq = (const float*)d_in[6];
    const float* bk = (const float*)d_in[7];
    const float* bv = (const float*)d_in[8];
    float* out = (float*)d_out;

    char* ws = (char*)d_ws;
    _Float16* WtAll = (_Float16*)ws;                    // 3 * 65536 * 2 B
    _Float16* qbuf  = (_Float16*)(ws + 393216);         // 16384*128*2 = 4 MB
    _Float16* kbuf  = (_Float16*)(ws + 4587520);        // 4 MB
    _Float16* vtbuf = (_Float16*)(ws + 8781824);        // 4 MB (transposed)

    wt_kernel<<<dim3(256, 3), 256, 0, stream>>>(Wq, Wk, Wv, WtAll);
    proj_kernel<<<dim3(512, 3), 256, 0, stream>>>(q_in, k_in, v_in, WtAll, bq,
                                                  bk, bv, qbuf, kbuf, vtbuf);
    attn_kernel<<<dim3(256), 512, 0, stream>>>(qbuf, kbuf, vtbuf, out);
}

// Round 9
// 178.639 us; speedup vs baseline: 1.0684x; 1.0684x over previous
//
#include <hip/hip_runtime.h>
#include <math.h>

typedef _Float16 half8_t __attribute__((ext_vector_type(8)));
typedef _Float16 half4_t __attribute__((ext_vector_type(4)));
typedef _Float16 half2_t __attribute__((ext_vector_type(2)));
typedef float f32x4 __attribute__((ext_vector_type(4)));
typedef float f32x16 __attribute__((ext_vector_type(16)));
typedef unsigned int uint32x4 __attribute__((ext_vector_type(4)));

#define MFMA16(a, b, c) __builtin_amdgcn_mfma_f32_16x16x32_f16((a), (b), (c), 0, 0, 0)
#define MFMA32(a, b, c) __builtin_amdgcn_mfma_f32_32x32x16_f16((a), (b), (c), 0, 0, 0)

// log2(e) / sqrt(128): fold softmax scale AND exp->exp2 conversion into q.
#define SCALE_Q (0.08838834764831845f * 1.44269504088896340736f)

// Barrier that does NOT drain vmcnt: LDS writes made visible (lgkmcnt(0)),
// but in-flight global prefetch loads stay outstanding across the barrier.
// (__syncthreads emits s_waitcnt vmcnt(0) — that drain was the serializer
// pinning proj at ~41 us across 4 structural variants, and attn's T14.)
#define BAR_NO_VMDRAIN()                                      \
    do {                                                      \
        asm volatile("s_waitcnt lgkmcnt(0)" ::: "memory");    \
        __builtin_amdgcn_s_barrier();                         \
    } while (0)

static __device__ inline unsigned int pkh(float a, float b) {
    half2_t h;
    h[0] = (_Float16)a;
    h[1] = (_Float16)b;
    return __builtin_bit_cast(unsigned int, h);
}

// ---------------------------------------------------------------------------
// Kernel 0: W [512][128] fp32  ->  Wt [128][512] fp16   (x3 for q,k,v)
// ---------------------------------------------------------------------------
__global__ __launch_bounds__(256) void wt_kernel(const float* __restrict__ Wq,
                                                 const float* __restrict__ Wk,
                                                 const float* __restrict__ Wv,
                                                 _Float16* __restrict__ WtAll) {
    int y = blockIdx.y;
    const float* W = (y == 0) ? Wq : (y == 1) ? Wk : Wv;
    int idx = blockIdx.x * 256 + threadIdx.x;
    int kk = idx >> 7;
    int d  = idx & 127;
    WtAll[y * 65536 + d * 512 + kk] = (_Float16)W[idx];
}

// ---------------------------------------------------------------------------
// Kernel 1: projection GEMM v6.  C[16384][128] = X[16384][512] @ W + b
// = v4 (depth-2 named-regset prefetch, dbuf LDS, 64-row tiles, grid (256,3))
// with the K-loop __syncthreads replaced by lgkmcnt(0) + raw s_barrier:
// prefetch loads now survive the barrier; the compiler's register-dependency
// vmcnt(4) before each ds_write is the counted wait (T4 mechanism).
// ---------------------------------------------------------------------------
__global__ __launch_bounds__(256) void proj_kernel(
    const float* __restrict__ q_in, const float* __restrict__ k_in,
    const float* __restrict__ v_in, const _Float16* __restrict__ WtAll,
    const float* __restrict__ biasq, const float* __restrict__ biask,
    const float* __restrict__ biasv,
    _Float16* __restrict__ qbuf, _Float16* __restrict__ kbuf,
    _Float16* __restrict__ vtbuf) {
    int y = blockIdx.y;
    const float* x = (y == 0) ? q_in : (y == 1) ? k_in : v_in;
    const _Float16* Wt = WtAll + y * 65536;
    const float* bias = (y == 0) ? biasq : (y == 1) ? biask : biasv;
    int row0 = blockIdx.x * 64;

    __shared__ _Float16 smem[15360];   // 30,720 B; epilogue overlays staging
    _Float16* AsA = smem;              // [64][40]   (BK=32 +8 pad) even tiles
    _Float16* WsA = smem + 2560;       // [128][40]
    _Float16* AsB = smem + 7680;       // odd tiles
    _Float16* WsB = smem + 10240;

    int tid = threadIdx.x;
    int wave = tid >> 6, lane = tid & 63, quad = lane >> 4, l16 = lane & 15;
    int wm = (wave & 1) * 32, wn = (wave >> 1) * 64;
    int arow = tid >> 2, acol = (tid & 3) * 8;    // A stage: 64 rows x 32 k
    int wrow = tid >> 1, wcol = (tid & 1) * 16;   // W stage: 128 d x 32 k

    f32x4 acc[2][4] = {};

#define LOADSET(KB, A0, A1, W0, W1)                                          \
    {                                                                        \
        const float4* ap =                                                   \
            (const float4*)(x + (size_t)(row0 + arow) * 512 + (KB) + acol);  \
        A0 = ap[0]; A1 = ap[1];                                              \
        const half8_t* wp =                                                  \
            (const half8_t*)(Wt + wrow * 512 + (KB) + wcol);                 \
        W0 = wp[0]; W1 = wp[1];                                              \
    }
#define STORESET(AS, WS, A0, A1, W0, W1)                                     \
    {                                                                        \
        half8_t h;                                                           \
        h[0] = (_Float16)A0.x; h[1] = (_Float16)A0.y;                        \
        h[2] = (_Float16)A0.z; h[3] = (_Float16)A0.w;                        \
        h[4] = (_Float16)A1.x; h[5] = (_Float16)A1.y;                        \
        h[6] = (_Float16)A1.z; h[7] = (_Float16)A1.w;                        \
        *(half8_t*)&(AS)[arow * 40 + acol]     = h;                          \
        *(half8_t*)&(WS)[wrow * 40 + wcol]     = W0;                         \
        *(half8_t*)&(WS)[wrow * 40 + wcol + 8] = W1;                         \
    }
#define COMPUTE(AS, WS)                                                      \
    {                                                                        \
        half8_t af[2], bf[4];                                                \
        for (int mt = 0; mt < 2; mt++)                                       \
            af[mt] =                                                         \
                *(const half8_t*)&(AS)[(wm + mt * 16 + l16) * 40 + quad * 8];\
        for (int nt = 0; nt < 4; nt++)                                       \
            bf[nt] =                                                         \
                *(const half8_t*)&(WS)[(wn + nt * 16 + l16) * 40 + quad * 8];\
        for (int mt = 0; mt < 2; mt++)                                       \
            for (int nt = 0; nt < 4; nt++)                                   \
                acc[mt][nt] = MFMA16(af[mt], bf[nt], acc[mt][nt]);           \
    }

    float4 ea0, ea1; half8_t ew0, ew1;   // even regset (tiles 0,64,128,...)
    float4 oa0, oa1; half8_t ow0, ow1;   // odd regset  (tiles 32,96,...)

    // prologue: tiles 0 and 32 in flight; write tile 0 (odd set stays
    // outstanding across the barrier)
    LOADSET(0, ea0, ea1, ew0, ew1);
    LOADSET(32, oa0, oa1, ow0, ow1);
    STORESET(AsA, WsA, ea0, ea1, ew0, ew1);
    BAR_NO_VMDRAIN();

    for (int kb = 0; kb < 512; kb += 64) {
        // even step: compute tile kb from bufA
        if (kb + 64 < 512) LOADSET(kb + 64, ea0, ea1, ew0, ew1);
        COMPUTE(AsA, WsA);
        STORESET(AsB, WsB, oa0, oa1, ow0, ow1);   // vmcnt(4) via reg-dep
        BAR_NO_VMDRAIN();
        // odd step: compute tile kb+32 from bufB
        if (kb + 96 < 512) LOADSET(kb + 96, oa0, oa1, ow0, ow1);
        COMPUTE(AsB, WsB);
        if (kb + 64 < 512) {
            STORESET(AsA, WsA, ea0, ea1, ew0, ew1);
        }
        BAR_NO_VMDRAIN();
    }
#undef LOADSET
#undef STORESET
#undef COMPUTE

    // Epilogue: bias + scale, assemble tile in LDS, coalesced store.
    float scale = (y == 0) ? SCALE_Q : 1.0f;
    if (y < 2) {
        // row-major [s][d] tile in smem[64][136]
        for (int mt = 0; mt < 2; mt++)
            for (int nt = 0; nt < 4; nt++) {
                int d = wn + nt * 16 + l16;
                float b = bias[d];
                for (int r = 0; r < 4; r++)
                    smem[(wm + mt * 16 + quad * 4 + r) * 136 + d] =
                        (_Float16)((acc[mt][nt][r] + b) * scale);
            }
        __syncthreads();
        int srow = tid >> 2, sc = (tid & 3) * 32;
        _Float16* outp =
            ((y == 0) ? qbuf : kbuf) + (size_t)(row0 + srow) * 128 + sc;
        for (int i = 0; i < 4; i++)
            *(half8_t*)(outp + i * 8) =
                *(const half8_t*)&smem[srow * 136 + sc + i * 8];
    } else {
        // transposed [d][s] tile in smem[128][72]
        for (int mt = 0; mt < 2; mt++)
            for (int nt = 0; nt < 4; nt++) {
                int d = wn + nt * 16 + l16;
                float b = bias[d];
                half4_t pk;
                for (int r = 0; r < 4; r++)
                    pk[r] = (_Float16)(acc[mt][nt][r] + b);
                *(half4_t*)&smem[d * 72 + wm + mt * 16 + quad * 4] = pk;
            }
        __syncthreads();
        int d = tid >> 1, off = (tid & 1) * 32;
        int bbn = row0 >> 11, s0 = row0 & 2047;
        _Float16* outp = vtbuf + ((size_t)bbn * 128 + d) * 2048 + s0 + off;
        for (int i = 0; i < 4; i++)
            *(half8_t*)(outp + i * 8) =
                *(const half8_t*)&smem[d * 72 + off + i * 8];
    }
}

// ---------------------------------------------------------------------------
// Kernel 2: flash attention, 32x32 MFMA, in-register P (no Pt LDS).
// XCD-aware mapping (T1): bb = blockIdx.x & 7. 1 block = 64 q rows, 8 waves:
// {g = kv-half} x {qsub} x {kt}. Swapped QK^T (S^T = K Q^T) puts q = lane&31;
// softmax folds with ONE shfl_xor(32); P -> PV B-operand via cross-hi
// exchange (T12). O^T in regs; 4 partial (O,m,l) chains merged in LDS at end.
// Per-tile barrier is lgkmcnt(0)+raw s_barrier: the T14 prefetch loads now
// genuinely stay in flight across the barrier (no vmcnt(0) drain).
// ---------------------------------------------------------------------------
__global__ __launch_bounds__(512, 2) void attn_kernel(
    const _Float16* __restrict__ qbuf, const _Float16* __restrict__ kbuf,
    const _Float16* __restrict__ vtbuf, float* __restrict__ out) {
    int bb = blockIdx.x & 7;            // XCD-aligned batch mapping (T1)
    int q0 = (blockIdx.x >> 3) * 64;
    int tid = threadIdx.x, wave = tid >> 6, lane = tid & 63;
    int g = wave >> 2, qsub = (wave >> 1) & 1, kt = wave & 1;
    int l32 = lane & 31, hi = lane >> 5, hi8 = hi * 8;

    __shared__ _Float16 smem[71680];   // 143,360 B
    _Float16* KsA = smem + g * 35840;            // [64][136]
    _Float16* KsB = KsA + 8704;
    _Float16* VsA = smem + g * 35840 + 17408;    // [128][72]  (V^T: [d][key])
    _Float16* VsB = VsA + 9216;

    // Q fragments: B-frag for 32x32x16: B[k=hi*8+j][q=l32]
    half8_t qf[8];
    {
        const _Float16* qrow =
            qbuf + ((size_t)bb * 2048 + q0 + qsub * 32 + l32) * 128 + hi8;
#pragma unroll
        for (int kc = 0; kc < 8; kc++)
            qf[kc] = *(const half8_t*)(qrow + kc * 16);
    }

    const _Float16* kbase = kbuf + ((size_t)bb * 2048 + g * 1024) * 128;
    const _Float16* vbase = vtbuf + (size_t)bb * 128 * 2048 + g * 1024;

    int tg = tid & 255;                           // thread within kv-group
    int krow = tg >> 2, kcol = (tg & 3) * 32;     // K stage: 64 x 128
    int vrow = tg >> 1, vcol = (tg & 1) * 32;     // V stage: 128 x 64

    // prologue: stage tile 0 into buffer A
    {
        const half8_t* ks = (const half8_t*)(kbase + (size_t)krow * 128 + kcol);
        half8_t k0 = ks[0], k1 = ks[1], k2 = ks[2], k3 = ks[3];
        const half8_t* vs = (const half8_t*)(vbase + (size_t)vrow * 2048 + vcol);
        half8_t v0 = vs[0], v1 = vs[1], v2 = vs[2], v3 = vs[3];
        *(half8_t*)&KsA[krow * 136 + kcol]      = k0;
        *(half8_t*)&KsA[krow * 136 + kcol + 8]  = k1;
        *(half8_t*)&KsA[krow * 136 + kcol + 16] = k2;
        *(half8_t*)&KsA[krow * 136 + kcol + 24] = k3;
        *(half8_t*)&VsA[vrow * 72 + vcol]       = v0;
        *(half8_t*)&VsA[vrow * 72 + vcol + 8]   = v1;
        *(half8_t*)&VsA[vrow * 72 + vcol + 16]  = v2;
        *(half8_t*)&VsA[vrow * 72 + vcol + 24]  = v3;
    }
    BAR_NO_VMDRAIN();

    f32x16 acc0 = {}, acc1 = {}, acc2 = {}, acc3 = {};
    float m = -INFINITY, l = 0.0f;

    for (int it = 0; it < 16; ++it) {
        bool more = it < 15;
        half8_t nk0, nk1, nk2, nk3, nv0, nv1, nv2, nv3;
        if (more) {   // T14: issue next-tile loads before compute
            const half8_t* ks =
                (const half8_t*)(kbase + (size_t)((it + 1) * 64 + krow) * 128 + kcol);
            nk0 = ks[0]; nk1 = ks[1]; nk2 = ks[2]; nk3 = ks[3];
            const half8_t* vs =
                (const half8_t*)(vbase + (size_t)vrow * 2048 + (it + 1) * 64 + vcol);
            nv0 = vs[0]; nv1 = vs[1]; nv2 = vs[2]; nv3 = vs[3];
        }

        // S^T[key][q] = K Q^T for this wave's 32 keys (kt subtile)
        f32x16 sf = {};
        __builtin_amdgcn_s_setprio(1);
#pragma unroll
        for (int kc = 0; kc < 8; kc++) {
            half8_t kf =
                *(const half8_t*)&KsA[(kt * 32 + l32) * 136 + kc * 16 + hi8];
            sf = MFMA32(kf, qf[kc], sf);
        }
        __builtin_amdgcn_s_setprio(0);

        // online softmax; q = l32 per lane; keys split across hi halves
        float mx = sf[0];
#pragma unroll
        for (int i = 1; i < 16; i++) mx = fmaxf(mx, sf[i]);
        mx = fmaxf(mx, __shfl_xor(mx, 32, 64));
        if (!__all(mx <= m + 8.0f)) {   // T13 defer-max (THR=8)
            float mn = fmaxf(m, mx);
            float al = exp2f(m - mn);
            l *= al;
            acc0 *= al; acc1 *= al; acc2 *= al; acc3 *= al;
            m = mn;
        }
        float p[16];
        float rs = 0.0f;
#pragma unroll
        for (int i = 0; i < 16; i++) {
            p[i] = exp2f(sf[i] - m);
            rs += p[i];
        }
        rs += __shfl_xor(rs, 32, 64);
        l += rs;

        // pack P (key = (r&3)+8*(r>>2)+4*hi), cross-hi exchange -> B-frags
        unsigned int u0 = pkh(p[0], p[1]),   u1 = pkh(p[2], p[3]);
        unsigned int u2 = pkh(p[4], p[5]),   u3 = pkh(p[6], p[7]);
        unsigned int u4 = pkh(p[8], p[9]),   u5 = pkh(p[10], p[11]);
        unsigned int u6 = pkh(p[12], p[13]), u7 = pkh(p[14], p[15]);
        unsigned int x00 = hi ? u0 : u2, x01 = hi ? u1 : u3;
        unsigned int x10 = hi ? u4 : u6, x11 = hi ? u5 : u7;
        unsigned int r00 = __shfl_xor(x00, 32, 64), r01 = __shfl_xor(x01, 32, 64);
        unsigned int r10 = __shfl_xor(x10, 32, 64), r11 = __shfl_xor(x11, 32, 64);
        uint32x4 b0u, b1u;
        b0u[0] = hi ? r00 : u0; b0u[1] = hi ? r01 : u1;
        b0u[2] = hi ? u2 : r00; b0u[3] = hi ? u3 : r01;
        b1u[0] = hi ? r10 : u4; b1u[1] = hi ? r11 : u5;
        b1u[2] = hi ? u6 : r10; b1u[3] = hi ? u7 : r11;
        half8_t pb0 = __builtin_bit_cast(half8_t, b0u);
        half8_t pb1 = __builtin_bit_cast(half8_t, b1u);

        // O^T[d][q] += V^T P^T  (A = V^T rows d, B = P^T cols q)
        __builtin_amdgcn_s_setprio(1);
        {
            half8_t v0 = *(const half8_t*)&VsA[(0 * 32 + l32) * 72 + kt * 32 + hi8];
            acc0 = MFMA32(v0, pb0, acc0);
            half8_t v1 = *(const half8_t*)&VsA[(0 * 32 + l32) * 72 + kt * 32 + 16 + hi8];
            acc0 = MFMA32(v1, pb1, acc0);
            half8_t v2 = *(const half8_t*)&VsA[(1 * 32 + l32) * 72 + kt * 32 + hi8];
            acc1 = MFMA32(v2, pb0, acc1);
            half8_t v3 = *(const half8_t*)&VsA[(1 * 32 + l32) * 72 + kt * 32 + 16 + hi8];
            acc1 = MFMA32(v3, pb1, acc1);
            half8_t v4 = *(const half8_t*)&VsA[(2 * 32 + l32) * 72 + kt * 32 + hi8];
            acc2 = MFMA32(v4, pb0, acc2);
            half8_t v5 = *(const half8_t*)&VsA[(2 * 32 + l32) * 72 + kt * 32 + 16 + hi8];
            acc2 = MFMA32(v5, pb1, acc2);
            half8_t v6 = *(const half8_t*)&VsA[(3 * 32 + l32) * 72 + kt * 32 + hi8];
            acc3 = MFMA32(v6, pb0, acc3);
            half8_t v7 = *(const half8_t*)&VsA[(3 * 32 + l32) * 72 + kt * 32 + 16 + hi8];
            acc3 = MFMA32(v7, pb1, acc3);
        }
        __builtin_amdgcn_s_setprio(0);

        if (more) {
            *(half8_t*)&KsB[krow * 136 + kcol]      = nk0;
            *(half8_t*)&KsB[krow * 136 + kcol + 8]  = nk1;
            *(half8_t*)&KsB[krow * 136 + kcol + 16] = nk2;
            *(half8_t*)&KsB[krow * 136 + kcol + 24] = nk3;
            *(half8_t*)&VsB[vrow * 72 + vcol]       = nv0;
            *(half8_t*)&VsB[vrow * 72 + vcol + 8]   = nv1;
            *(half8_t*)&VsB[vrow * 72 + vcol + 16]  = nv2;
            *(half8_t*)&VsB[vrow * 72 + vcol + 24]  = nv3;
        }
        BAR_NO_VMDRAIN();
        _Float16* tmp;
        tmp = KsA; KsA = KsB; KsB = tmp;
        tmp = VsA; VsA = VsB; VsB = tmp;
    }

    // -----------------------------------------------------------------------
    // Merge the 4 partial chains (g,kt) per qsub. Tree: kt-pairs, then g-pairs.
    // Scratch overlays dead K/V LDS: R1[4 regions][128][33] f32 + ml[4][64].
    // -----------------------------------------------------------------------
    float* R1 = (float*)smem;
    const int RS = 33;
    int wid2 = g * 2 + qsub;
    float* Om = R1 + wid2 * (128 * RS);
    float* Ml = R1 + 4 * 128 * RS + wid2 * 64;

#define STORE_ACC(DST, A, DT)                                             \
    {                                                                     \
        _Pragma("unroll") for (int r = 0; r < 16; r++) {                  \
            int d = (r & 3) + 8 * (r >> 2) + 4 * hi + 32 * (DT);          \
            (DST)[d * RS + l32] = (A)[r];                                 \
        }                                                                 \
    }
#define MERGE_ACC(SRC, A, DT)                                             \
    {                                                                     \
        _Pragma("unroll") for (int r = 0; r < 16; r++) {                  \
            int d = (r & 3) + 8 * (r >> 2) + 4 * hi + 32 * (DT);          \
            (A)[r] = (A)[r] * sa + (SRC)[d * RS + l32] * sb;              \
        }                                                                 \
    }

    if (kt == 1) {
        STORE_ACC(Om, acc0, 0); STORE_ACC(Om, acc1, 1);
        STORE_ACC(Om, acc2, 2); STORE_ACC(Om, acc3, 3);
        if (hi == 0) { Ml[l32] = m; Ml[32 + l32] = l; }
    }
    __syncthreads();
    if (kt == 0) {
        float m1 = Ml[l32], l1 = Ml[32 + l32];
        float mf = fmaxf(m, m1);
        float sa = exp2f(m - mf), sb = exp2f(m1 - mf);
        l = l * sa + l1 * sb;
        m = mf;
        MERGE_ACC(Om, acc0, 0); MERGE_ACC(Om, acc1, 1);
        MERGE_ACC(Om, acc2, 2); MERGE_ACC(Om, acc3, 3);
    }
    __syncthreads();
    if (kt == 0 && g == 1) {
        float* Om2 = R1 + qsub * (128 * RS);
        float* Ml2 = R1 + 4 * 128 * RS + qsub * 64;
        STORE_ACC(Om2, acc0, 0); STORE_ACC(Om2, acc1, 1);
        STORE_ACC(Om2, acc2, 2); STORE_ACC(Om2, acc3, 3);
        if (hi == 0) { Ml2[l32] = m; Ml2[32 + l32] = l; }
    }
    __syncthreads();
    if (kt == 0 && g == 0) {
        float* Om2 = R1 + qsub * (128 * RS);
        float* Ml2 = R1 + 4 * 128 * RS + qsub * 64;
        float m1 = Ml2[l32], l1 = Ml2[32 + l32];
        float mf = fmaxf(m, m1);
        float sa = exp2f(m - mf), sb = exp2f(m1 - mf);
        float lf = l * sa + l1 * sb;
        float inv = 1.0f / lf;
        float* op = out + ((size_t)bb * 2048 + q0 + qsub * 32 + l32) * 128;
#define FINAL_ACC(A, DT)                                                  \
        {                                                                 \
            _Pragma("unroll") for (int r = 0; r < 16; r++) {              \
                int d = (r & 3) + 8 * (r >> 2) + 4 * hi + 32 * (DT);      \
                op[d] = ((A)[r] * sa + Om2[d * RS + l32] * sb) * inv;     \
            }                                                             \
        }
        FINAL_ACC(acc0, 0); FINAL_ACC(acc1, 1);
        FINAL_ACC(acc2, 2); FINAL_ACC(acc3, 3);
#undef FINAL_ACC
    }
#undef STORE_ACC
#undef MERGE_ACC
}

// ---------------------------------------------------------------------------
extern "C" void kernel_launch(void* const* d_in, const int* in_sizes, int n_in,
                              void* d_out, int out_size, void* d_ws,
                              size_t ws_size, hipStream_t stream) {
    const float* q_in = (const float*)d_in[0];
    const float* k_in = (const float*)d_in[1];
    const float* v_in = (const float*)d_in[2];
    const float* Wq = (const float*)d_in[3];
    const float* Wk = (const float*)d_in[4];
    const float* Wv = (const float*)d_in[5];
    const float* bq = (const float*)d_in[6];
    const float* bk = (const float*)d_in[7];
    const float* bv = (const float*)d_in[8];
    float* out = (float*)d_out;

    char* ws = (char*)d_ws;
    _Float16* WtAll = (_Float16*)ws;                    // 3 * 65536 * 2 B
    _Float16* qbuf  = (_Float16*)(ws + 393216);         // 16384*128*2 = 4 MB
    _Float16* kbuf  = (_Float16*)(ws + 4587520);        // 4 MB
    _Float16* vtbuf = (_Float16*)(ws + 8781824);        // 4 MB (transposed)

    wt_kernel<<<dim3(256, 3), 256, 0, stream>>>(Wq, Wk, Wv, WtAll);
    proj_kernel<<<dim3(256, 3), 256, 0, stream>>>(q_in, k_in, v_in, WtAll, bq,
                                                  bk, bv, qbuf, kbuf, vtbuf);
    attn_kernel<<<dim3(256), 512, 0, stream>>>(qbuf, kbuf, vtbuf, out);
}